// Round 14
// baseline (210.236 us; speedup 1.0000x reference)
//
#include <hip/hip_runtime.h>
#include <hip/hip_bf16.h>
#include <stdint.h>

#define DIM     1024
#define SEQ     2048
#define NTOK    4096
#define HEADS   8
#define DH      64
#define AINNER  512
#define FFI     4096
#define FUSED   8832
#define HCOLS   4608   // 512 attn-out cols + 4096 gated-ff cols

typedef __attribute__((ext_vector_type(8))) short short8;
typedef __attribute__((ext_vector_type(4))) short short4v;
typedef __attribute__((ext_vector_type(4))) float f32x4;

__device__ __forceinline__ short f2bf(float f) {
  union { float f; uint32_t u; } v; v.f = f;
  uint32_t r = v.u + 0x7fffu + ((v.u >> 16) & 1u);
  return (short)(r >> 16);
}
__device__ __forceinline__ float bf2f(short s) {
  union { uint32_t u; float f; } v; v.u = ((uint32_t)(uint16_t)s) << 16;
  return v.f;
}
__device__ __forceinline__ void g2l16(const void* g, void* l) {
  __builtin_amdgcn_global_load_lds((const __attribute__((address_space(1))) void*)g,
                                   (__attribute__((address_space(3))) void*)l, 16, 0, 0);
}

#define PW10 asm volatile("s_waitcnt vmcnt(10)\ns_barrier" ::: "memory")
#define PH_W0 asm volatile("s_waitcnt vmcnt(0)\ns_barrier" ::: "memory")
#define PH_B  asm volatile("s_barrier" ::: "memory")

// ---------------- prep: both weight transposes + layernorm in one dispatch --
__global__ __launch_bounds__(256) void k_prep(const float* __restrict__ wf,
                                              const float* __restrict__ wao,
                                              const float* __restrict__ wfo,
                                              const float* __restrict__ x,
                                              const float* __restrict__ gamma,
                                              short* __restrict__ WtF,
                                              short* __restrict__ Wt2,
                                              short* __restrict__ xn) {
  __shared__ short tile[32][33];
  __shared__ float red[8];
  int bid = blockIdx.x;
  if (bid < 8832) {
    int bx = bid % 276, by = bid / 276;
    int c0 = bx * 32, r0 = by * 32;
    int tx = threadIdx.x & 31, ty = threadIdx.x >> 5;
#pragma unroll
    for (int i = 0; i < 32; i += 8)
      tile[ty + i][tx] = f2bf(wf[(size_t)(r0 + ty + i) * FUSED + c0 + tx]);
    __syncthreads();
#pragma unroll
    for (int i = 0; i < 32; i += 8)
      WtF[(size_t)(c0 + ty + i) * DIM + r0 + tx] = tile[tx][ty + i];
  } else if (bid < 13440) {
    int idx = bid - 8832;
    int bx = idx & 31, by = idx >> 5;
    int c0 = bx * 32, r0 = by * 32;
    int tx = threadIdx.x & 31, ty = threadIdx.x >> 5;
#pragma unroll
    for (int i = 0; i < 32; i += 8) {
      int r = r0 + ty + i;
      float v = (r < AINNER) ? wao[(size_t)r * DIM + c0 + tx]
                             : wfo[(size_t)(r - AINNER) * DIM + c0 + tx];
      tile[ty + i][tx] = f2bf(v);
    }
    __syncthreads();
#pragma unroll
    for (int i = 0; i < 32; i += 8)
      Wt2[(size_t)(c0 + ty + i) * HCOLS + r0 + tx] = tile[tx][ty + i];
  } else {
    int row = bid - 13440;
    int t = threadIdx.x;
    const float4* xr = (const float4*)(x + (size_t)row * DIM);
    float4 v = xr[t];
    float s = v.x + v.y + v.z + v.w;
    float s2 = v.x * v.x + v.y * v.y + v.z * v.z + v.w * v.w;
#pragma unroll
    for (int m = 1; m < 64; m <<= 1) { s += __shfl_xor(s, m); s2 += __shfl_xor(s2, m); }
    int w = t >> 6;
    if ((t & 63) == 0) { red[w] = s; red[4 + w] = s2; }
    __syncthreads();
    s = red[0] + red[1] + red[2] + red[3];
    s2 = red[4] + red[5] + red[6] + red[7];
    float mu = s * (1.f / DIM);
    float rs = rsqrtf(s2 * (1.f / DIM) - mu * mu + 1e-5f);
    const float4* g4 = (const float4*)gamma;
    float4 g = g4[t];
    short4v o;
    o.x = f2bf((v.x - mu) * rs * g.x);
    o.y = f2bf((v.y - mu) * rs * g.y);
    o.z = f2bf((v.z - mu) * rs * g.z);
    o.w = f2bf((v.w - mu) * rs * g.w);
    ((short4v*)(xn + (size_t)row * DIM))[t] = o;
  }
}

// ---------------- p1: fused qkv + silu(gate)*ffx GEMM, deep half-slot pipe --
// grid (37,16), 512 thr = 8 waves, 256-row A tiles, BK=64, 128KB LDS dbuf.
// Fused blocks: pair schedule — stage A1(t+1)@ph0->side dbn; A0/B0/B1(t+2)
// @ph1/2/3 -> side db (slot just retired this tile; entry barrier of the
// staging phase orders it after all waves' reads). Uniform vmcnt(10)+barrier
// ph0-2 gives each pair ~7 phases (~1.5 tiles) of latency slack. Tail: self-
// reload (same source -> benign). Reads: ph0 a1,bF; ph1 bG; ph2 a2; ph3 none.
__global__ __launch_bounds__(512, 2) void p1(const short* __restrict__ A,
                                             const short* __restrict__ Bt,
                                             short* __restrict__ qb,
                                             short* __restrict__ kbf,
                                             short* __restrict__ vtb,
                                             short* __restrict__ H) {
  extern __shared__ __align__(16) short S[];
  int tid = threadIdx.x, l = tid & 63, w = tid >> 6;
  int hw = blockIdx.y * 37 + blockIdx.x;      // 592 blocks
  int tile = (hw & 7) * 74 + (hw >> 3);       // XCD-contiguous remap
  int c = tile / 74, j = tile % 74;           // chunk c: 64 fused + 10 qkv
  bool fused = j < 64;
  int bx, by;
  if (fused) { int f = c * 64 + j; by = f >> 5; bx = f & 31; }
  else       { int q = c * 10 + (j - 64); by = q / 5; bx = 32 + q % 5; }
  int mBase = by * 256;
  int b0row = fused ? (640 + bx * 128) : ((bx - 32) * 128);
  int b1row = 4736 + bx * 128;

  int srow = w * 8 + (l >> 3);
  int cs = (l & 7) ^ (l >> 3);
  const short* Ag = A + (size_t)(mBase + srow) * DIM + cs * 8;
  const short* Bg0 = Bt + (size_t)(b0row + srow) * DIM + cs * 8;
  const short* Bg1 = Bt + (size_t)(b1row + srow) * DIM + cs * 8;
  int dsto = w * 512 + l * 8;

#define STG_A0(kt, db) { _Pragma("unroll") for (int i = 0; i < 2; ++i) \
    g2l16(Ag + (size_t)(i * 64) * DIM + (kt) * 64, S + (db) * 16384 + i * 4096 + dsto); }
#define STG_A1(kt, db) { _Pragma("unroll") for (int i = 2; i < 4; ++i) \
    g2l16(Ag + (size_t)(i * 64) * DIM + (kt) * 64, S + (db) * 16384 + i * 4096 + dsto); }
#define STG_B0(kt, db) { _Pragma("unroll") for (int i = 0; i < 2; ++i) \
    g2l16(Bg0 + (size_t)(i * 64) * DIM + (kt) * 64, S + 32768 + (db) * 16384 + i * 4096 + dsto); }
#define STG_B1(kt, db) { _Pragma("unroll") for (int i = 0; i < 2; ++i) \
    g2l16(Bg1 + (size_t)(i * 64) * DIM + (kt) * 64, S + 32768 + (db) * 16384 + 8192 + i * 4096 + dsto); }

  const int NT = DIM / 64;  // 16
  int c0 = l & 15, kg = l >> 4, cx = l & 7;
  int ch0 = (kg ^ cx) * 8, ch1 = ((4 + kg) ^ cx) * 8;
  int r0 = (l >> 4) * 4;
  f32x4 zero = {0.f, 0.f, 0.f, 0.f};

  if (!fused) {
    // ---- qkv path: simple stage-all loop (unchanged) ----
    STG_A0(0, 0); STG_A1(0, 0); STG_B0(0, 0);
    int wm = w >> 2, wn = w & 3;
    f32x4 acc[8][2];
#pragma unroll
    for (int m = 0; m < 8; ++m) { acc[m][0] = zero; acc[m][1] = zero; }
    for (int kt = 0; kt < NT; ++kt) {
      int db = kt & 1, dbn = db ^ 1;
      PH_W0;
      if (kt + 1 < NT) { STG_A0(kt + 1, dbn); STG_A1(kt + 1, dbn); STG_B0(kt + 1, dbn); }
      const short* Ab = S + db * 16384;
      const short* Bb = S + 32768 + db * 16384;
#pragma unroll
      for (int kkh = 0; kkh < 2; ++kkh) {
        int ch8 = kkh ? ch1 : ch0;
        short8 b0 = *(const short8*)(Bb + (wn * 32 + c0) * 64 + ch8);
        short8 b1 = *(const short8*)(Bb + (wn * 32 + 16 + c0) * 64 + ch8);
        __builtin_amdgcn_s_setprio(1);
#pragma unroll
        for (int m = 0; m < 8; ++m) {
          short8 a = *(const short8*)(Ab + (wm * 128 + m * 16 + c0) * 64 + ch8);
          acc[m][0] = __builtin_amdgcn_mfma_f32_16x16x32_bf16(a, b0, acc[m][0], 0, 0, 0);
          acc[m][1] = __builtin_amdgcn_mfma_f32_16x16x32_bf16(a, b1, acc[m][1], 0, 0, 0);
        }
        __builtin_amdgcn_s_setprio(0);
      }
    }
#pragma unroll
    for (int m = 0; m < 8; ++m)
#pragma unroll
      for (int n = 0; n < 2; ++n)
#pragma unroll
        for (int r = 0; r < 4; ++r) {
          float val = acc[m][n][r];
          int row = mBase + wm * 128 + m * 16 + r0 + r;
          int col = (bx - 32) * 128 + wn * 32 + n * 16 + c0;
          if (col < AINNER)
            qb[(size_t)row * AINNER + col] = f2bf(val);
          else if (col < AINNER + DH)
            kbf[(size_t)row * DH + (col - AINNER)] = f2bf(val);
          else
            vtb[((size_t)(row >> 11) * DH + (col - AINNER - DH)) * SEQ +
                (row & (SEQ - 1))] = f2bf(val);
        }
    return;
  }

  // ---- fused path: deep half-slot pipeline ----
  // prologue: tiles 0 (4 pairs, side 0) + 1 (3 pairs, side 1); A1(1)@t0.ph0
  STG_A0(0, 0); STG_B0(0, 0); STG_B1(0, 0); STG_A1(0, 0);
  STG_A0(1, 1); STG_B0(1, 1); STG_B1(1, 1);
  int ra = (w >> 2) * 64, rb = (w & 3) * 32;
  f32x4 acc[2][2][4][2];
#pragma unroll
  for (int a = 0; a < 2; ++a)
#pragma unroll
    for (int b = 0; b < 2; ++b)
#pragma unroll
      for (int m = 0; m < 4; ++m)
#pragma unroll
        for (int n = 0; n < 2; ++n) acc[a][b][m][n] = zero;

  for (int kt = 0; kt < NT; ++kt) {
    int db = kt & 1, dbn = db ^ 1;
    int tA1 = (kt + 1 < NT) ? kt + 1 : kt;   // A1 pair of tile kt+1 -> side dbn
    int tN  = (kt + 2 < NT) ? kt + 2 : kt;   // A0/B0/B1 of tile kt+2 -> side db
    const short* Ab = S + db * 16384;
    const short* Bb = S + 32768 + db * 16384;
    short8 a1[4][2], a2[4][2], bF[2][2], bG[2][2];
    // ---- ph0: (A0,F); stage A1(kt+1) ----
    PW10;
#pragma unroll
    for (int m = 0; m < 4; ++m) {
      a1[m][0] = *(const short8*)(Ab + (ra + m * 16 + c0) * 64 + ch0);
      a1[m][1] = *(const short8*)(Ab + (ra + m * 16 + c0) * 64 + ch1);
    }
#pragma unroll
    for (int n = 0; n < 2; ++n) {
      bF[n][0] = *(const short8*)(Bb + (rb + n * 16 + c0) * 64 + ch0);
      bF[n][1] = *(const short8*)(Bb + (rb + n * 16 + c0) * 64 + ch1);
    }
    STG_A1(tA1, dbn);
    __builtin_amdgcn_s_setprio(1);
#pragma unroll
    for (int m = 0; m < 4; ++m)
#pragma unroll
      for (int n = 0; n < 2; ++n) {
        acc[0][0][m][n] = __builtin_amdgcn_mfma_f32_16x16x32_bf16(a1[m][0], bF[n][0], acc[0][0][m][n], 0, 0, 0);
        acc[0][0][m][n] = __builtin_amdgcn_mfma_f32_16x16x32_bf16(a1[m][1], bF[n][1], acc[0][0][m][n], 0, 0, 0);
      }
    __builtin_amdgcn_s_setprio(0);
    // ---- ph1: (A0,G); stage A0(kt+2) into retired slot ----
    PW10;
#pragma unroll
    for (int n = 0; n < 2; ++n) {
      bG[n][0] = *(const short8*)(Bb + 8192 + (rb + n * 16 + c0) * 64 + ch0);
      bG[n][1] = *(const short8*)(Bb + 8192 + (rb + n * 16 + c0) * 64 + ch1);
    }
    STG_A0(tN, db);
    __builtin_amdgcn_s_setprio(1);
#pragma unroll
    for (int m = 0; m < 4; ++m)
#pragma unroll
      for (int n = 0; n < 2; ++n) {
        acc[0][1][m][n] = __builtin_amdgcn_mfma_f32_16x16x32_bf16(a1[m][0], bG[n][0], acc[0][1][m][n], 0, 0, 0);
        acc[0][1][m][n] = __builtin_amdgcn_mfma_f32_16x16x32_bf16(a1[m][1], bG[n][1], acc[0][1][m][n], 0, 0, 0);
      }
    __builtin_amdgcn_s_setprio(0);
    // ---- ph2: (A1,G); stage B0(kt+2) ----
    PW10;
#pragma unroll
    for (int m = 0; m < 4; ++m) {
      a2[m][0] = *(const short8*)(Ab + 8192 + (ra + m * 16 + c0) * 64 + ch0);
      a2[m][1] = *(const short8*)(Ab + 8192 + (ra + m * 16 + c0) * 64 + ch1);
    }
    STG_B0(tN, db);
    __builtin_amdgcn_s_setprio(1);
#pragma unroll
    for (int m = 0; m < 4; ++m)
#pragma unroll
      for (int n = 0; n < 2; ++n) {
        acc[1][1][m][n] = __builtin_amdgcn_mfma_f32_16x16x32_bf16(a2[m][0], bG[n][0], acc[1][1][m][n], 0, 0, 0);
        acc[1][1][m][n] = __builtin_amdgcn_mfma_f32_16x16x32_bf16(a2[m][1], bG[n][1], acc[1][1][m][n], 0, 0, 0);
      }
    __builtin_amdgcn_s_setprio(0);
    // ---- ph3: (A1,F); stage B1(kt+2) ----
    PH_B;
    STG_B1(tN, db);
    __builtin_amdgcn_s_setprio(1);
#pragma unroll
    for (int m = 0; m < 4; ++m)
#pragma unroll
      for (int n = 0; n < 2; ++n) {
        acc[1][0][m][n] = __builtin_amdgcn_mfma_f32_16x16x32_bf16(a2[m][0], bF[n][0], acc[1][0][m][n], 0, 0, 0);
        acc[1][0][m][n] = __builtin_amdgcn_mfma_f32_16x16x32_bf16(a2[m][1], bF[n][1], acc[1][0][m][n], 0, 0, 0);
      }
    __builtin_amdgcn_s_setprio(0);
  }
  asm volatile("s_waitcnt vmcnt(0)" ::: "memory");  // drain dangling reloads
#undef STG_A0
#undef STG_A1
#undef STG_B0
#undef STG_B1

#pragma unroll
  for (int a = 0; a < 2; ++a)
#pragma unroll
    for (int m = 0; m < 4; ++m)
#pragma unroll
      for (int n = 0; n < 2; ++n)
#pragma unroll
        for (int r = 0; r < 4; ++r) {
          int row = mBase + a * 128 + ra + m * 16 + r0 + r;
          int col = bx * 128 + rb + n * 16 + c0;   // F-panel col 0..4095
          float g = acc[a][1][m][n][r];
          float sg = g / (1.f + __expf(-g));
          H[(size_t)row * HCOLS + AINNER + col] = f2bf(sg * acc[a][0][m][n][r]);
        }
}

// ---------------- out-GEMM: 256x256 split-K=4, deep half-slot pipe ----------
__global__ __launch_bounds__(512, 2) void gemm_s(const short* __restrict__ A,
                                                 const short* __restrict__ Bt,
                                                 short* __restrict__ part) {
  extern __shared__ __align__(16) short S[];
  int tid = threadIdx.x, l = tid & 63, w = tid >> 6;
  int hw = (blockIdx.z * 16 + blockIdx.y) * 4 + blockIdx.x;  // 256 blocks
  int tile = (hw & 7) * 32 + (hw >> 3);
  int bx = tile & 3, by = (tile >> 2) & 15, bz = tile >> 6;
  int mBase = by * 256, nBase = bx * 256;
  int kOff = bz * 1152;

  int srow = w * 8 + (l >> 3);
  int cs = (l & 7) ^ (l >> 3);
  const short* Ag = A + (size_t)(mBase + srow) * HCOLS + kOff + cs * 8;
  const short* Bg = Bt + (size_t)(nBase + srow) * HCOLS + kOff + cs * 8;
  int dsto = w * 512 + l * 8;

#define SG_A0(kt, db) { _Pragma("unroll") for (int i = 0; i < 2; ++i) \
    g2l16(Ag + (size_t)(i * 64) * HCOLS + (kt) * 64, S + (db) * 16384 + i * 4096 + dsto); }
#define SG_A1(kt, db) { _Pragma("unroll") for (int i = 2; i < 4; ++i) \
    g2l16(Ag + (size_t)(i * 64) * HCOLS + (kt) * 64, S + (db) * 16384 + i * 4096 + dsto); }
#define SG_B0(kt, db) { _Pragma("unroll") for (int i = 0; i < 2; ++i) \
    g2l16(Bg + (size_t)(i * 64) * HCOLS + (kt) * 64, S + 32768 + (db) * 16384 + i * 4096 + dsto); }
#define SG_B1(kt, db) { _Pragma("unroll") for (int i = 2; i < 4; ++i) \
    g2l16(Bg + (size_t)(i * 64) * HCOLS + (kt) * 64, S + 32768 + (db) * 16384 + i * 4096 + dsto); }

  const int NT = 18;
  SG_A0(0, 0); SG_B0(0, 0); SG_B1(0, 0); SG_A1(0, 0);
  SG_A0(1, 1); SG_B0(1, 1); SG_B1(1, 1);

  int c0 = l & 15, kg = l >> 4, cx = l & 7;
  int ch0 = (kg ^ cx) * 8, ch1 = ((4 + kg) ^ cx) * 8;
  int ra = (w >> 2) * 64, rb = (w & 3) * 32;
  f32x4 zero = {0.f, 0.f, 0.f, 0.f};
  f32x4 acc[2][2][4][2];
#pragma unroll
  for (int a = 0; a < 2; ++a)
#pragma unroll
    for (int b = 0; b < 2; ++b)
#pragma unroll
      for (int m = 0; m < 4; ++m)
#pragma unroll
        for (int n = 0; n < 2; ++n) acc[a][b][m][n] = zero;

  for (int kt = 0; kt < NT; ++kt) {
    int db = kt & 1, dbn = db ^ 1;
    int tA1 = (kt + 1 < NT) ? kt + 1 : kt;
    int tN  = (kt + 2 < NT) ? kt + 2 : kt;
    const short* Ab = S + db * 16384;
    const short* Bb = S + 32768 + db * 16384;
    short8 a1[4][2], a2[4][2], bF[2][2], bG[2][2];
    // ph0: (A0, Blo); stage A1(kt+1)
    PW10;
#pragma unroll
    for (int m = 0; m < 4; ++m) {
      a1[m][0] = *(const short8*)(Ab + (ra + m * 16 + c0) * 64 + ch0);
      a1[m][1] = *(const short8*)(Ab + (ra + m * 16 + c0) * 64 + ch1);
    }
#pragma unroll
    for (int n = 0; n < 2; ++n) {
      bF[n][0] = *(const short8*)(Bb + (rb + n * 16 + c0) * 64 + ch0);
      bF[n][1] = *(const short8*)(Bb + (rb + n * 16 + c0) * 64 + ch1);
    }
    SG_A1(tA1, dbn);
    __builtin_amdgcn_s_setprio(1);
#pragma unroll
    for (int m = 0; m < 4; ++m)
#pragma unroll
      for (int n = 0; n < 2; ++n) {
        acc[0][0][m][n] = __builtin_amdgcn_mfma_f32_16x16x32_bf16(a1[m][0], bF[n][0], acc[0][0][m][n], 0, 0, 0);
        acc[0][0][m][n] = __builtin_amdgcn_mfma_f32_16x16x32_bf16(a1[m][1], bF[n][1], acc[0][0][m][n], 0, 0, 0);
      }
    __builtin_amdgcn_s_setprio(0);
    // ph1: (A0, Bhi); stage A0(kt+2)
    PW10;
#pragma unroll
    for (int n = 0; n < 2; ++n) {
      bG[n][0] = *(const short8*)(Bb + 8192 + (rb + n * 16 + c0) * 64 + ch0);
      bG[n][1] = *(const short8*)(Bb + 8192 + (rb + n * 16 + c0) * 64 + ch1);
    }
    SG_A0(tN, db);
    __builtin_amdgcn_s_setprio(1);
#pragma unroll
    for (int m = 0; m < 4; ++m)
#pragma unroll
      for (int n = 0; n < 2; ++n) {
        acc[0][1][m][n] = __builtin_amdgcn_mfma_f32_16x16x32_bf16(a1[m][0], bG[n][0], acc[0][1][m][n], 0, 0, 0);
        acc[0][1][m][n] = __builtin_amdgcn_mfma_f32_16x16x32_bf16(a1[m][1], bG[n][1], acc[0][1][m][n], 0, 0, 0);
      }
    __builtin_amdgcn_s_setprio(0);
    // ph2: (A1, Bhi); stage B0(kt+2)
    PW10;
#pragma unroll
    for (int m = 0; m < 4; ++m) {
      a2[m][0] = *(const short8*)(Ab + 8192 + (ra + m * 16 + c0) * 64 + ch0);
      a2[m][1] = *(const short8*)(Ab + 8192 + (ra + m * 16 + c0) * 64 + ch1);
    }
    SG_B0(tN, db);
    __builtin_amdgcn_s_setprio(1);
#pragma unroll
    for (int m = 0; m < 4; ++m)
#pragma unroll
      for (int n = 0; n < 2; ++n) {
        acc[1][1][m][n] = __builtin_amdgcn_mfma_f32_16x16x32_bf16(a2[m][0], bG[n][0], acc[1][1][m][n], 0, 0, 0);
        acc[1][1][m][n] = __builtin_amdgcn_mfma_f32_16x16x32_bf16(a2[m][1], bG[n][1], acc[1][1][m][n], 0, 0, 0);
      }
    __builtin_amdgcn_s_setprio(0);
    // ph3: (A1, Blo); stage B1(kt+2)
    PH_B;
    SG_B1(tN, db);
    __builtin_amdgcn_s_setprio(1);
#pragma unroll
    for (int m = 0; m < 4; ++m)
#pragma unroll
      for (int n = 0; n < 2; ++n) {
        acc[1][0][m][n] = __builtin_amdgcn_mfma_f32_16x16x32_bf16(a2[m][0], bF[n][0], acc[1][0][m][n], 0, 0, 0);
        acc[1][0][m][n] = __builtin_amdgcn_mfma_f32_16x16x32_bf16(a2[m][1], bF[n][1], acc[1][0][m][n], 0, 0, 0);
      }
    __builtin_amdgcn_s_setprio(0);
  }
  asm volatile("s_waitcnt vmcnt(0)" ::: "memory");
#undef SG_A0
#undef SG_A1
#undef SG_B0
#undef SG_B1

  int r0 = (l >> 4) * 4;
#pragma unroll
  for (int a = 0; a < 2; ++a)
#pragma unroll
    for (int b = 0; b < 2; ++b)
#pragma unroll
      for (int m = 0; m < 4; ++m)
#pragma unroll
        for (int n = 0; n < 2; ++n)
#pragma unroll
          for (int r = 0; r < 4; ++r) {
            int row = mBase + a * 128 + ra + m * 16 + r0 + r;
            int col = nBase + b * 128 + rb + n * 16 + c0;
            part[(size_t)bz * (NTOK * DIM) + (size_t)row * DIM + col] = f2bf(acc[a][b][m][n][r]);
          }
}

__global__ __launch_bounds__(256) void k_red(const short* __restrict__ part,
                                             float* __restrict__ out) {
  int i = (blockIdx.x * 256 + threadIdx.x) * 8;
  float s[8] = {0.f, 0.f, 0.f, 0.f, 0.f, 0.f, 0.f, 0.f};
#pragma unroll
  for (int ks = 0; ks < 4; ++ks) {
    short8 v = *(const short8*)(part + (size_t)ks * (NTOK * DIM) + i);
#pragma unroll
    for (int jj = 0; jj < 8; ++jj) s[jj] += bf2f(v[jj]);
  }
  float4 lo = {s[0], s[1], s[2], s[3]};
  float4 hi = {s[4], s[5], s[6], s[7]};
  *(float4*)(out + i) = lo;
  *(float4*)(out + i + 4) = hi;
}

// ---------------- flash attention (unchanged) -------------------------------
__global__ __launch_bounds__(256) void k_attn(const short* __restrict__ qb,
                                              const short* __restrict__ kb,
                                              const short* __restrict__ vt,
                                              short* __restrict__ H) {
  __shared__ __align__(16) short Qs[64 * 64];
  __shared__ __align__(16) short Ks[128 * 64];
  __shared__ __align__(16) short Vs[64 * 128];
  __shared__ __align__(16) short Ps[4][16 * 128];
  int t = threadIdx.x, l = t & 63, w = t >> 6;
  int qt = blockIdx.x, bh = blockIdx.y;
  int b = bh >> 3, h = bh & 7;
  int q0 = qt * 64;

  int srow = w * 8 + (l >> 3);
  int schunk = (l & 7) ^ (l >> 3);
  {
    const short* Qg = qb + (size_t)(b * SEQ + q0 + srow) * AINNER + h * DH + schunk * 8;
    short* qs = Qs + w * 512 + l * 8;
#pragma unroll
    for (int i = 0; i < 2; ++i) g2l16(Qg + (size_t)(i * 32) * AINNER, qs + i * 2048);
  }
  const short* Kg = kb + (size_t)(b * SEQ + srow) * DH + schunk * 8;
  short* ksl = Ks + w * 512 + l * 8;
  int vrow = w * 4 + (l >> 4);
  int vchunk = (l & 15) ^ (vrow & 7);
  const short* Vg = vt + (size_t)b * DH * SEQ + (size_t)vrow * SEQ + vchunk * 8;
  short* vsl = Vs + w * 512 + l * 8;

#pragma unroll
  for (int i = 0; i < 4; ++i) {
    g2l16(Kg + (size_t)(i * 32) * DH, ksl + i * 2048);
    g2l16(Vg + (size_t)(i * 16) * SEQ, vsl + i * 2048);
  }

  float m_run[4], l_run[4];
  f32x4 zero = {0.f, 0.f, 0.f, 0.f};
  f32x4 Oacc[4];
#pragma unroll
  for (int r = 0; r < 4; ++r) { m_run[r] = -1e30f; l_run[r] = 0.f; }
#pragma unroll
  for (int n = 0; n < 4; ++n) Oacc[n] = zero;

  int c0 = l & 15, kg = l >> 4, cx = l & 7;
  short* pw = Ps[w];

  for (int kv0 = 0; kv0 < SEQ; kv0 += 128) {
    asm volatile("s_waitcnt vmcnt(0)\ns_barrier" ::: "memory");

    f32x4 sacc[8];
#pragma unroll
    for (int n = 0; n < 8; ++n) sacc[n] = zero;
#pragma unroll
    for (int kk = 0; kk < 2; ++kk) {
      int rr = w * 16 + c0;
      short8 aq = *(const short8*)(Qs + rr * 64 + ((kk * 4 + kg) ^ cx) * 8);
#pragma unroll
      for (int n = 0; n < 8; ++n) {
        int kr = n * 16 + c0;
        short8 bk = *(const short8*)(Ks + kr * 64 + ((kk * 4 + kg) ^ cx) * 8);
        sacc[n] = __builtin_amdgcn_mfma_f32_16x16x32_bf16(aq, bk, sacc[n], 0, 0, 0);
      }
    }
#pragma unroll
    for (int r = 0; r < 4; ++r) {
      float mx = -1e30f;
#pragma unroll
      for (int n = 0; n < 8; ++n) {
        sacc[n][r] *= 0.125f;
        mx = fmaxf(mx, sacc[n][r]);
      }
#pragma unroll
      for (int msk = 1; msk < 16; msk <<= 1) mx = fmaxf(mx, __shfl_xor(mx, msk));
      float nm = fmaxf(m_run[r], mx);
      float corr = __expf(m_run[r] - nm);
      m_run[r] = nm;
      float rs = 0.f;
#pragma unroll
      for (int n = 0; n < 8; ++n) {
        float p = __expf(sacc[n][r] - nm);
        sacc[n][r] = p;
        rs += p;
      }
#pragma unroll
      for (int msk = 1; msk < 16; msk <<= 1) rs += __shfl_xor(rs, msk);
      l_run[r] = l_run[r] * corr + rs;
      Oacc[0][r] *= corr; Oacc[1][r] *= corr; Oacc[2][r] *= corr; Oacc[3][r] *= corr;
    }
#pragma unroll
    for (int n = 0; n < 8; ++n)
#pragma unroll
      for (int r = 0; r < 4; ++r) {
        int pr = (l >> 4) * 4 + r;
        int pc = n * 16 + c0;
        pw[pr * 128 + ((pc >> 3) ^ (pr & 7)) * 8 + (pc & 7)] = f2bf(sacc[n][r]);
      }
    asm volatile("s_waitcnt lgkmcnt(0)" ::: "memory");
#pragma unroll
    for (int kk = 0; kk < 4; ++kk) {
      int pr = c0;
      short8 ap = *(const short8*)(pw + pr * 128 + ((kk * 4 + kg) ^ cx) * 8);
#pragma unroll
      for (int n = 0; n < 4; ++n) {
        int vr = n * 16 + c0;
        short8 bv = *(const short8*)(Vs + vr * 128 + ((kk * 4 + kg) ^ (vr & 7)) * 8);
        Oacc[n] = __builtin_amdgcn_mfma_f32_16x16x32_bf16(ap, bv, Oacc[n], 0, 0, 0);
      }
    }
    __syncthreads();
    int nx = kv0 + 128;
    if (nx < SEQ) {
#pragma unroll
      for (int i = 0; i < 4; ++i) {
        g2l16(Kg + (size_t)(nx + i * 32) * DH, ksl + i * 2048);
        g2l16(Vg + nx + (size_t)(i * 16) * SEQ, vsl + i * 2048);
      }
    }
  }
#pragma unroll
  for (int r = 0; r < 4; ++r) {
    float inv = 1.f / l_run[r];
    int row = b * SEQ + q0 + w * 16 + (l >> 4) * 4 + r;
#pragma unroll
    for (int n = 0; n < 4; ++n) {
      int col = h * DH + n * 16 + c0;
      H[(size_t)row * HCOLS + col] = f2bf(Oacc[n][r] * inv);
    }
  }
}

// ----------------------------------------------------------------------------
extern "C" void kernel_launch(void* const* d_in, const int* in_sizes, int n_in,
                              void* d_out, int out_size, void* d_ws, size_t ws_size,
                              hipStream_t stream) {
  const float* x     = (const float*)d_in[0];
  const float* gamma = (const float*)d_in[1];
  const float* w_f   = (const float*)d_in[2];
  const float* w_ao  = (const float*)d_in[3];
  const float* w_fo  = (const float*)d_in[4];
  float* out = (float*)d_out;

  char* ws = (char*)d_ws;
  size_t o = 0;
  short* WtF = (short*)(ws + o); o += (size_t)FUSED * DIM * 2;
  short* Wt2 = (short*)(ws + o); o += (size_t)DIM * HCOLS * 2;
  short* xn  = (short*)(ws + o); o += (size_t)NTOK * DIM * 2;
  short* qb  = (short*)(ws + o); o += (size_t)NTOK * AINNER * 2;
  short* kbf = (short*)(ws + o); o += (size_t)NTOK * DH * 2;
  short* vtb = (short*)(ws + o); o += (size_t)NTOK * DH * 2;
  short* H   = (short*)(ws + o); o += (size_t)NTOK * HCOLS * 2;
  short* part = (short*)(ws + o);

  k_prep<<<17536, 256, 0, stream>>>(w_f, w_ao, w_fo, x, gamma, WtF, Wt2, xn);
  p1<<<dim3(37, 16), 512, 131072, stream>>>(xn, WtF, qb, kbf, vtb, H);
  k_attn<<<dim3(32, 16), 256, 0, stream>>>(qb, kbf, vtb, H);
  gemm_s<<<dim3(4, 16, 4), 512, 131072, stream>>>(H, Wt2, part);
  k_red<<<NTOK * DIM / 2048, 256, 0, stream>>>(part, out);
}

// Round 15
// 206.588 us; speedup vs baseline: 1.0177x; 1.0177x over previous
//
#include <hip/hip_runtime.h>
#include <hip/hip_bf16.h>
#include <stdint.h>

#define DIM     1024
#define SEQ     2048
#define NTOK    4096
#define HEADS   8
#define DH      64
#define AINNER  512
#define FFI     4096
#define FUSED   8832
#define HCOLS   4608   // 512 attn-out cols + 4096 gated-ff cols

typedef __attribute__((ext_vector_type(8))) short short8;
typedef __attribute__((ext_vector_type(4))) short short4v;
typedef __attribute__((ext_vector_type(4))) float f32x4;

__device__ __forceinline__ short f2bf(float f) {
  union { float f; uint32_t u; } v; v.f = f;
  uint32_t r = v.u + 0x7fffu + ((v.u >> 16) & 1u);
  return (short)(r >> 16);
}
__device__ __forceinline__ float bf2f(short s) {
  union { uint32_t u; float f; } v; v.u = ((uint32_t)(uint16_t)s) << 16;
  return v.f;
}
__device__ __forceinline__ void g2l16(const void* g, void* l) {
  __builtin_amdgcn_global_load_lds((const __attribute__((address_space(1))) void*)g,
                                   (__attribute__((address_space(3))) void*)l, 16, 0, 0);
}

#define PH_W4 asm volatile("s_waitcnt vmcnt(4)\ns_barrier" ::: "memory")
#define PH_W2 asm volatile("s_waitcnt vmcnt(2)\ns_barrier" ::: "memory")
#define PH_W0 asm volatile("s_waitcnt vmcnt(0)\ns_barrier" ::: "memory")
#define PH_B  asm volatile("s_barrier" ::: "memory")

// ---------------- prep: vectorized transposes + layernorm, one dispatch -----
// 64x64 tiles: float4 loads (16B/lane), LDS short[64][65], short4 writes.
// blocks [0,2208): w_fused; [2208,3360): w2 (512-seam is 64-aligned); rest LN.
__global__ __launch_bounds__(256) void k_prep(const float* __restrict__ wf,
                                              const float* __restrict__ wao,
                                              const float* __restrict__ wfo,
                                              const float* __restrict__ x,
                                              const float* __restrict__ gamma,
                                              short* __restrict__ WtF,
                                              short* __restrict__ Wt2,
                                              short* __restrict__ xn) {
  __shared__ short tile[64][65];
  __shared__ float red[8];
  int bid = blockIdx.x;
  int t = threadIdx.x;
  if (bid < 3360) {
    bool wfm = bid < 2208;
    int r0, c0, srcld, dstld;
    const float* src0;
    if (wfm) {
      int bx = bid % 138, by = bid / 138;          // 138 col-tiles x 16 row-tiles
      c0 = bx * 64; r0 = by * 64;
      src0 = wf; srcld = FUSED; dstld = DIM;
    } else {
      int idx = bid - 2208;
      int by = idx >> 4, bx = idx & 15;            // 72 row-tiles x 16 col-tiles
      r0 = by * 64; c0 = bx * 64;
      src0 = (r0 < AINNER) ? wao : wfo;
      if (r0 >= AINNER) r0 -= AINNER;
      srcld = DIM; dstld = HCOLS;
    }
    int tx4 = t & 15, ty = t >> 4;                 // 16 lanes x float4 = 64 cols
#pragma unroll
    for (int i = 0; i < 4; ++i) {
      float4 v = *(const float4*)(src0 + (size_t)(r0 + ty + 16 * i) * srcld + c0 + tx4 * 4);
      tile[ty + 16 * i][tx4 * 4 + 0] = f2bf(v.x);
      tile[ty + 16 * i][tx4 * 4 + 1] = f2bf(v.y);
      tile[ty + 16 * i][tx4 * 4 + 2] = f2bf(v.z);
      tile[ty + 16 * i][tx4 * 4 + 3] = f2bf(v.w);
    }
    __syncthreads();
    // write: dst row = c0+orow (global col), cols r0+oc*4.. (global rows)
    int dr0 = wfm ? 0 : 0;                         // dst row base offset (none)
    int rbase = wfm ? (bid / 138) * 64 : ((bid - 2208) >> 4) * 64;  // original r0 pre-seam
    short* dst = wfm ? WtF : Wt2;
    int oc = t & 15, orw = t >> 4;                 // 16 col-quads x 16 rows/pass
#pragma unroll
    for (int i = 0; i < 4; ++i) {
      int orow = orw + 16 * i;
      short4v o;
      o.x = tile[oc * 4 + 0][orow];
      o.y = tile[oc * 4 + 1][orow];
      o.z = tile[oc * 4 + 2][orow];
      o.w = tile[oc * 4 + 3][orow];
      *(short4v*)(dst + (size_t)(c0 + orow) * dstld + rbase + oc * 4) = o;
    }
    (void)dr0;
  } else {
    int row = bid - 3360;
    const float4* xr = (const float4*)(x + (size_t)row * DIM);
    float4 v = xr[t];
    float s = v.x + v.y + v.z + v.w;
    float s2 = v.x * v.x + v.y * v.y + v.z * v.z + v.w * v.w;
#pragma unroll
    for (int m = 1; m < 64; m <<= 1) { s += __shfl_xor(s, m); s2 += __shfl_xor(s2, m); }
    int w = t >> 6;
    if ((t & 63) == 0) { red[w] = s; red[4 + w] = s2; }
    __syncthreads();
    s = red[0] + red[1] + red[2] + red[3];
    s2 = red[4] + red[5] + red[6] + red[7];
    float mu = s * (1.f / DIM);
    float rs = rsqrtf(s2 * (1.f / DIM) - mu * mu + 1e-5f);
    const float4* g4 = (const float4*)gamma;
    float4 g = g4[t];
    short4v o;
    o.x = f2bf((v.x - mu) * rs * g.x);
    o.y = f2bf((v.y - mu) * rs * g.y);
    o.z = f2bf((v.z - mu) * rs * g.z);
    o.w = f2bf((v.w - mu) * rs * g.w);
    ((short4v*)(xn + (size_t)row * DIM))[t] = o;
  }
}

// ---------------- p1: fused qkv + silu(gate)*ffx GEMM, convoy phases (R13) --
__global__ __launch_bounds__(512, 2) void p1(const short* __restrict__ A,
                                             const short* __restrict__ Bt,
                                             short* __restrict__ qb,
                                             short* __restrict__ kbf,
                                             short* __restrict__ vtb,
                                             short* __restrict__ H) {
  extern __shared__ __align__(16) short S[];
  int tid = threadIdx.x, l = tid & 63, w = tid >> 6;
  int hw = blockIdx.y * 37 + blockIdx.x;      // 592 blocks
  int tile = (hw & 7) * 74 + (hw >> 3);       // XCD-contiguous remap
  int c = tile / 74, j = tile % 74;           // chunk c: 64 fused + 10 qkv
  bool fused = j < 64;
  int bx, by;
  if (fused) { int f = c * 64 + j; by = f >> 5; bx = f & 31; }
  else       { int q = c * 10 + (j - 64); by = q / 5; bx = 32 + q % 5; }
  int mBase = by * 256;
  int b0row = fused ? (640 + bx * 128) : ((bx - 32) * 128);
  int b1row = 4736 + bx * 128;

  int srow = w * 8 + (l >> 3);
  int cs = (l & 7) ^ (l >> 3);
  const short* Ag = A + (size_t)(mBase + srow) * DIM + cs * 8;
  const short* Bg0 = Bt + (size_t)(b0row + srow) * DIM + cs * 8;
  const short* Bg1 = Bt + (size_t)(b1row + srow) * DIM + cs * 8;
  int dsto = w * 512 + l * 8;

#define STG_A0(kt, db) { _Pragma("unroll") for (int i = 0; i < 2; ++i) \
    g2l16(Ag + (size_t)(i * 64) * DIM + (kt) * 64, S + (db) * 16384 + i * 4096 + dsto); }
#define STG_A1(kt, db) { _Pragma("unroll") for (int i = 2; i < 4; ++i) \
    g2l16(Ag + (size_t)(i * 64) * DIM + (kt) * 64, S + (db) * 16384 + i * 4096 + dsto); }
#define STG_B0(kt, db) { _Pragma("unroll") for (int i = 0; i < 2; ++i) \
    g2l16(Bg0 + (size_t)(i * 64) * DIM + (kt) * 64, S + 32768 + (db) * 16384 + i * 4096 + dsto); }
#define STG_B1(kt, db) { _Pragma("unroll") for (int i = 0; i < 2; ++i) \
    g2l16(Bg1 + (size_t)(i * 64) * DIM + (kt) * 64, S + 32768 + (db) * 16384 + 8192 + i * 4096 + dsto); }

  const int NT = DIM / 64;  // 16
  int c0 = l & 15, kg = l >> 4, cx = l & 7;
  int ch0 = (kg ^ cx) * 8, ch1 = ((4 + kg) ^ cx) * 8;
  int r0 = (l >> 4) * 4;
  f32x4 zero = {0.f, 0.f, 0.f, 0.f};

  if (!fused) {
    STG_A0(0, 0); STG_A1(0, 0); STG_B0(0, 0);
    int wm = w >> 2, wn = w & 3;
    f32x4 acc[8][2];
#pragma unroll
    for (int m = 0; m < 8; ++m) { acc[m][0] = zero; acc[m][1] = zero; }
    for (int kt = 0; kt < NT; ++kt) {
      int db = kt & 1, dbn = db ^ 1;
      PH_W0;
      if (kt + 1 < NT) { STG_A0(kt + 1, dbn); STG_A1(kt + 1, dbn); STG_B0(kt + 1, dbn); }
      const short* Ab = S + db * 16384;
      const short* Bb = S + 32768 + db * 16384;
#pragma unroll
      for (int kkh = 0; kkh < 2; ++kkh) {
        int ch8 = kkh ? ch1 : ch0;
        short8 b0 = *(const short8*)(Bb + (wn * 32 + c0) * 64 + ch8);
        short8 b1 = *(const short8*)(Bb + (wn * 32 + 16 + c0) * 64 + ch8);
        __builtin_amdgcn_s_setprio(1);
#pragma unroll
        for (int m = 0; m < 8; ++m) {
          short8 a = *(const short8*)(Ab + (wm * 128 + m * 16 + c0) * 64 + ch8);
          acc[m][0] = __builtin_amdgcn_mfma_f32_16x16x32_bf16(a, b0, acc[m][0], 0, 0, 0);
          acc[m][1] = __builtin_amdgcn_mfma_f32_16x16x32_bf16(a, b1, acc[m][1], 0, 0, 0);
        }
        __builtin_amdgcn_s_setprio(0);
      }
    }
#pragma unroll
    for (int m = 0; m < 8; ++m)
#pragma unroll
      for (int n = 0; n < 2; ++n)
#pragma unroll
        for (int r = 0; r < 4; ++r) {
          float val = acc[m][n][r];
          int row = mBase + wm * 128 + m * 16 + r0 + r;
          int col = (bx - 32) * 128 + wn * 32 + n * 16 + c0;
          if (col < AINNER)
            qb[(size_t)row * AINNER + col] = f2bf(val);
          else if (col < AINNER + DH)
            kbf[(size_t)row * DH + (col - AINNER)] = f2bf(val);
          else
            vtb[((size_t)(row >> 11) * DH + (col - AINNER - DH)) * SEQ +
                (row & (SEQ - 1))] = f2bf(val);
        }
    return;
  }

  STG_A0(0, 0); STG_B0(0, 0); STG_B1(0, 0); STG_A1(0, 0);
  int ra = (w >> 2) * 64, rb = (w & 3) * 32;
  f32x4 acc[2][2][4][2];
#pragma unroll
  for (int a = 0; a < 2; ++a)
#pragma unroll
    for (int b = 0; b < 2; ++b)
#pragma unroll
      for (int m = 0; m < 4; ++m)
#pragma unroll
        for (int n = 0; n < 2; ++n) acc[a][b][m][n] = zero;

  for (int kt = 0; kt < NT; ++kt) {
    int db = kt & 1, dbn = db ^ 1;
    bool st = kt + 1 < NT;
    const short* Ab = S + db * 16384;
    const short* Bb = S + 32768 + db * 16384;
    short8 a1[4][2], a2[4][2], bF[2][2], bG[2][2];
    // ph0: (A0, F)
    PH_W4;
#pragma unroll
    for (int m = 0; m < 4; ++m) {
      a1[m][0] = *(const short8*)(Ab + (ra + m * 16 + c0) * 64 + ch0);
      a1[m][1] = *(const short8*)(Ab + (ra + m * 16 + c0) * 64 + ch1);
    }
#pragma unroll
    for (int n = 0; n < 2; ++n) {
      bF[n][0] = *(const short8*)(Bb + (rb + n * 16 + c0) * 64 + ch0);
      bF[n][1] = *(const short8*)(Bb + (rb + n * 16 + c0) * 64 + ch1);
    }
    if (st) STG_A0(kt + 1, dbn);
    PH_B;
    __builtin_amdgcn_s_setprio(1);
#pragma unroll
    for (int m = 0; m < 4; ++m)
#pragma unroll
      for (int n = 0; n < 2; ++n) {
        acc[0][0][m][n] = __builtin_amdgcn_mfma_f32_16x16x32_bf16(a1[m][0], bF[n][0], acc[0][0][m][n], 0, 0, 0);
        acc[0][0][m][n] = __builtin_amdgcn_mfma_f32_16x16x32_bf16(a1[m][1], bF[n][1], acc[0][0][m][n], 0, 0, 0);
      }
    __builtin_amdgcn_s_setprio(0);
    // ph1: (A0, G)
    if (st) PH_W4; else PH_W2;
#pragma unroll
    for (int n = 0; n < 2; ++n) {
      bG[n][0] = *(const short8*)(Bb + 8192 + (rb + n * 16 + c0) * 64 + ch0);
      bG[n][1] = *(const short8*)(Bb + 8192 + (rb + n * 16 + c0) * 64 + ch1);
    }
    if (st) STG_B0(kt + 1, dbn);
    PH_B;
    __builtin_amdgcn_s_setprio(1);
#pragma unroll
    for (int m = 0; m < 4; ++m)
#pragma unroll
      for (int n = 0; n < 2; ++n) {
        acc[0][1][m][n] = __builtin_amdgcn_mfma_f32_16x16x32_bf16(a1[m][0], bG[n][0], acc[0][1][m][n], 0, 0, 0);
        acc[0][1][m][n] = __builtin_amdgcn_mfma_f32_16x16x32_bf16(a1[m][1], bG[n][1], acc[0][1][m][n], 0, 0, 0);
      }
    __builtin_amdgcn_s_setprio(0);
    // ph2: (A1, G)
    if (st) PH_W4; else PH_W0;
#pragma unroll
    for (int m = 0; m < 4; ++m) {
      a2[m][0] = *(const short8*)(Ab + 8192 + (ra + m * 16 + c0) * 64 + ch0);
      a2[m][1] = *(const short8*)(Ab + 8192 + (ra + m * 16 + c0) * 64 + ch1);
    }
    if (st) STG_B1(kt + 1, dbn);
    PH_B;
    __builtin_amdgcn_s_setprio(1);
#pragma unroll
    for (int m = 0; m < 4; ++m)
#pragma unroll
      for (int n = 0; n < 2; ++n) {
        acc[1][1][m][n] = __builtin_amdgcn_mfma_f32_16x16x32_bf16(a2[m][0], bG[n][0], acc[1][1][m][n], 0, 0, 0);
        acc[1][1][m][n] = __builtin_amdgcn_mfma_f32_16x16x32_bf16(a2[m][1], bG[n][1], acc[1][1][m][n], 0, 0, 0);
      }
    __builtin_amdgcn_s_setprio(0);
    // ph3: (A1, F) — register-only
    if (st) STG_A1(kt + 1, dbn);
    __builtin_amdgcn_s_setprio(1);
#pragma unroll
    for (int m = 0; m < 4; ++m)
#pragma unroll
      for (int n = 0; n < 2; ++n) {
        acc[1][0][m][n] = __builtin_amdgcn_mfma_f32_16x16x32_bf16(a2[m][0], bF[n][0], acc[1][0][m][n], 0, 0, 0);
        acc[1][0][m][n] = __builtin_amdgcn_mfma_f32_16x16x32_bf16(a2[m][1], bF[n][1], acc[1][0][m][n], 0, 0, 0);
      }
    __builtin_amdgcn_s_setprio(0);
  }
#undef STG_A0
#undef STG_A1
#undef STG_B0
#undef STG_B1

#pragma unroll
  for (int a = 0; a < 2; ++a)
#pragma unroll
    for (int m = 0; m < 4; ++m)
#pragma unroll
      for (int n = 0; n < 2; ++n)
#pragma unroll
        for (int r = 0; r < 4; ++r) {
          int row = mBase + a * 128 + ra + m * 16 + r0 + r;
          int col = bx * 128 + rb + n * 16 + c0;
          float g = acc[a][1][m][n][r];
          float sg = g / (1.f + __expf(-g));
          H[(size_t)row * HCOLS + AINNER + col] = f2bf(sg * acc[a][0][m][n][r]);
        }
}

// ---------------- out-GEMM: 256x256 split-K=4, convoy phases (R13) ----------
__global__ __launch_bounds__(512, 2) void gemm_s(const short* __restrict__ A,
                                                 const short* __restrict__ Bt,
                                                 short* __restrict__ part) {
  extern __shared__ __align__(16) short S[];
  int tid = threadIdx.x, l = tid & 63, w = tid >> 6;
  int hw = (blockIdx.z * 16 + blockIdx.y) * 4 + blockIdx.x;  // 256 blocks
  int tile = (hw & 7) * 32 + (hw >> 3);
  int bx = tile & 3, by = (tile >> 2) & 15, bz = tile >> 6;
  int mBase = by * 256, nBase = bx * 256;
  int kOff = bz * 1152;

  int srow = w * 8 + (l >> 3);
  int cs = (l & 7) ^ (l >> 3);
  const short* Ag = A + (size_t)(mBase + srow) * HCOLS + kOff + cs * 8;
  const short* Bg = Bt + (size_t)(nBase + srow) * HCOLS + kOff + cs * 8;
  int dsto = w * 512 + l * 8;

#define SG_A0(kt, db) { _Pragma("unroll") for (int i = 0; i < 2; ++i) \
    g2l16(Ag + (size_t)(i * 64) * HCOLS + (kt) * 64, S + (db) * 16384 + i * 4096 + dsto); }
#define SG_A1(kt, db) { _Pragma("unroll") for (int i = 2; i < 4; ++i) \
    g2l16(Ag + (size_t)(i * 64) * HCOLS + (kt) * 64, S + (db) * 16384 + i * 4096 + dsto); }
#define SG_B0(kt, db) { _Pragma("unroll") for (int i = 0; i < 2; ++i) \
    g2l16(Bg + (size_t)(i * 64) * HCOLS + (kt) * 64, S + 32768 + (db) * 16384 + i * 4096 + dsto); }
#define SG_B1(kt, db) { _Pragma("unroll") for (int i = 2; i < 4; ++i) \
    g2l16(Bg + (size_t)(i * 64) * HCOLS + (kt) * 64, S + 32768 + (db) * 16384 + i * 4096 + dsto); }

  const int NT = 18;
  SG_A0(0, 0); SG_B0(0, 0); SG_B1(0, 0); SG_A1(0, 0);

  int c0 = l & 15, kg = l >> 4, cx = l & 7;
  int ch0 = (kg ^ cx) * 8, ch1 = ((4 + kg) ^ cx) * 8;
  int ra = (w >> 2) * 64, rb = (w & 3) * 32;
  f32x4 zero = {0.f, 0.f, 0.f, 0.f};
  f32x4 acc[2][2][4][2];
#pragma unroll
  for (int a = 0; a < 2; ++a)
#pragma unroll
    for (int b = 0; b < 2; ++b)
#pragma unroll
      for (int m = 0; m < 4; ++m)
#pragma unroll
        for (int n = 0; n < 2; ++n) acc[a][b][m][n] = zero;

  for (int kt = 0; kt < NT; ++kt) {
    int db = kt & 1, dbn = db ^ 1;
    bool st = kt + 1 < NT;
    const short* Ab = S + db * 16384;
    const short* Bb = S + 32768 + db * 16384;
    short8 a1[4][2], a2[4][2], bF[2][2], bG[2][2];
    PH_W4;
#pragma unroll
    for (int m = 0; m < 4; ++m) {
      a1[m][0] = *(const short8*)(Ab + (ra + m * 16 + c0) * 64 + ch0);
      a1[m][1] = *(const short8*)(Ab + (ra + m * 16 + c0) * 64 + ch1);
    }
#pragma unroll
    for (int n = 0; n < 2; ++n) {
      bF[n][0] = *(const short8*)(Bb + (rb + n * 16 + c0) * 64 + ch0);
      bF[n][1] = *(const short8*)(Bb + (rb + n * 16 + c0) * 64 + ch1);
    }
    if (st) SG_A0(kt + 1, dbn);
    PH_B;
    __builtin_amdgcn_s_setprio(1);
#pragma unroll
    for (int m = 0; m < 4; ++m)
#pragma unroll
      for (int n = 0; n < 2; ++n) {
        acc[0][0][m][n] = __builtin_amdgcn_mfma_f32_16x16x32_bf16(a1[m][0], bF[n][0], acc[0][0][m][n], 0, 0, 0);
        acc[0][0][m][n] = __builtin_amdgcn_mfma_f32_16x16x32_bf16(a1[m][1], bF[n][1], acc[0][0][m][n], 0, 0, 0);
      }
    __builtin_amdgcn_s_setprio(0);
    if (st) PH_W4; else PH_W2;
#pragma unroll
    for (int n = 0; n < 2; ++n) {
      bG[n][0] = *(const short8*)(Bb + 8192 + (rb + n * 16 + c0) * 64 + ch0);
      bG[n][1] = *(const short8*)(Bb + 8192 + (rb + n * 16 + c0) * 64 + ch1);
    }
    if (st) SG_B0(kt + 1, dbn);
    PH_B;
    __builtin_amdgcn_s_setprio(1);
#pragma unroll
    for (int m = 0; m < 4; ++m)
#pragma unroll
      for (int n = 0; n < 2; ++n) {
        acc[0][1][m][n] = __builtin_amdgcn_mfma_f32_16x16x32_bf16(a1[m][0], bG[n][0], acc[0][1][m][n], 0, 0, 0);
        acc[0][1][m][n] = __builtin_amdgcn_mfma_f32_16x16x32_bf16(a1[m][1], bG[n][1], acc[0][1][m][n], 0, 0, 0);
      }
    __builtin_amdgcn_s_setprio(0);
    if (st) PH_W4; else PH_W0;
#pragma unroll
    for (int m = 0; m < 4; ++m) {
      a2[m][0] = *(const short8*)(Ab + 8192 + (ra + m * 16 + c0) * 64 + ch0);
      a2[m][1] = *(const short8*)(Ab + 8192 + (ra + m * 16 + c0) * 64 + ch1);
    }
    if (st) SG_B1(kt + 1, dbn);
    PH_B;
    __builtin_amdgcn_s_setprio(1);
#pragma unroll
    for (int m = 0; m < 4; ++m)
#pragma unroll
      for (int n = 0; n < 2; ++n) {
        acc[1][1][m][n] = __builtin_amdgcn_mfma_f32_16x16x32_bf16(a2[m][0], bG[n][0], acc[1][1][m][n], 0, 0, 0);
        acc[1][1][m][n] = __builtin_amdgcn_mfma_f32_16x16x32_bf16(a2[m][1], bG[n][1], acc[1][1][m][n], 0, 0, 0);
      }
    __builtin_amdgcn_s_setprio(0);
    if (st) SG_A1(kt + 1, dbn);
    __builtin_amdgcn_s_setprio(1);
#pragma unroll
    for (int m = 0; m < 4; ++m)
#pragma unroll
      for (int n = 0; n < 2; ++n) {
        acc[1][0][m][n] = __builtin_amdgcn_mfma_f32_16x16x32_bf16(a2[m][0], bF[n][0], acc[1][0][m][n], 0, 0, 0);
        acc[1][0][m][n] = __builtin_amdgcn_mfma_f32_16x16x32_bf16(a2[m][1], bF[n][1], acc[1][0][m][n], 0, 0, 0);
      }
    __builtin_amdgcn_s_setprio(0);
  }
#undef SG_A0
#undef SG_A1
#undef SG_B0
#undef SG_B1

  int r0 = (l >> 4) * 4;
#pragma unroll
  for (int a = 0; a < 2; ++a)
#pragma unroll
    for (int b = 0; b < 2; ++b)
#pragma unroll
      for (int m = 0; m < 4; ++m)
#pragma unroll
        for (int n = 0; n < 2; ++n)
#pragma unroll
          for (int r = 0; r < 4; ++r) {
            int row = mBase + a * 128 + ra + m * 16 + r0 + r;
            int col = nBase + b * 128 + rb + n * 16 + c0;
            part[(size_t)bz * (NTOK * DIM) + (size_t)row * DIM + col] = f2bf(acc[a][b][m][n][r]);
          }
}

__global__ __launch_bounds__(256) void k_red(const short* __restrict__ part,
                                             float* __restrict__ out) {
  int i = (blockIdx.x * 256 + threadIdx.x) * 8;
  float s[8] = {0.f, 0.f, 0.f, 0.f, 0.f, 0.f, 0.f, 0.f};
#pragma unroll
  for (int ks = 0; ks < 4; ++ks) {
    short8 v = *(const short8*)(part + (size_t)ks * (NTOK * DIM) + i);
#pragma unroll
    for (int jj = 0; jj < 8; ++jj) s[jj] += bf2f(v[jj]);
  }
  float4 lo = {s[0], s[1], s[2], s[3]};
  float4 hi = {s[4], s[5], s[6], s[7]};
  *(float4*)(out + i) = lo;
  *(float4*)(out + i + 4) = hi;
}

// ---------------- flash attention (unchanged) -------------------------------
__global__ __launch_bounds__(256) void k_attn(const short* __restrict__ qb,
                                              const short* __restrict__ kb,
                                              const short* __restrict__ vt,
                                              short* __restrict__ H) {
  __shared__ __align__(16) short Qs[64 * 64];
  __shared__ __align__(16) short Ks[128 * 64];
  __shared__ __align__(16) short Vs[64 * 128];
  __shared__ __align__(16) short Ps[4][16 * 128];
  int t = threadIdx.x, l = t & 63, w = t >> 6;
  int qt = blockIdx.x, bh = blockIdx.y;
  int b = bh >> 3, h = bh & 7;
  int q0 = qt * 64;

  int srow = w * 8 + (l >> 3);
  int schunk = (l & 7) ^ (l >> 3);
  {
    const short* Qg = qb + (size_t)(b * SEQ + q0 + srow) * AINNER + h * DH + schunk * 8;
    short* qs = Qs + w * 512 + l * 8;
#pragma unroll
    for (int i = 0; i < 2; ++i) g2l16(Qg + (size_t)(i * 32) * AINNER, qs + i * 2048);
  }
  const short* Kg = kb + (size_t)(b * SEQ + srow) * DH + schunk * 8;
  short* ksl = Ks + w * 512 + l * 8;
  int vrow = w * 4 + (l >> 4);
  int vchunk = (l & 15) ^ (vrow & 7);
  const short* Vg = vt + (size_t)b * DH * SEQ + (size_t)vrow * SEQ + vchunk * 8;
  short* vsl = Vs + w * 512 + l * 8;

#pragma unroll
  for (int i = 0; i < 4; ++i) {
    g2l16(Kg + (size_t)(i * 32) * DH, ksl + i * 2048);
    g2l16(Vg + (size_t)(i * 16) * SEQ, vsl + i * 2048);
  }

  float m_run[4], l_run[4];
  f32x4 zero = {0.f, 0.f, 0.f, 0.f};
  f32x4 Oacc[4];
#pragma unroll
  for (int r = 0; r < 4; ++r) { m_run[r] = -1e30f; l_run[r] = 0.f; }
#pragma unroll
  for (int n = 0; n < 4; ++n) Oacc[n] = zero;

  int c0 = l & 15, kg = l >> 4, cx = l & 7;
  short* pw = Ps[w];

  for (int kv0 = 0; kv0 < SEQ; kv0 += 128) {
    asm volatile("s_waitcnt vmcnt(0)\ns_barrier" ::: "memory");

    f32x4 sacc[8];
#pragma unroll
    for (int n = 0; n < 8; ++n) sacc[n] = zero;
#pragma unroll
    for (int kk = 0; kk < 2; ++kk) {
      int rr = w * 16 + c0;
      short8 aq = *(const short8*)(Qs + rr * 64 + ((kk * 4 + kg) ^ cx) * 8);
#pragma unroll
      for (int n = 0; n < 8; ++n) {
        int kr = n * 16 + c0;
        short8 bk = *(const short8*)(Ks + kr * 64 + ((kk * 4 + kg) ^ cx) * 8);
        sacc[n] = __builtin_amdgcn_mfma_f32_16x16x32_bf16(aq, bk, sacc[n], 0, 0, 0);
      }
    }
#pragma unroll
    for (int r = 0; r < 4; ++r) {
      float mx = -1e30f;
#pragma unroll
      for (int n = 0; n < 8; ++n) {
        sacc[n][r] *= 0.125f;
        mx = fmaxf(mx, sacc[n][r]);
      }
#pragma unroll
      for (int msk = 1; msk < 16; msk <<= 1) mx = fmaxf(mx, __shfl_xor(mx, msk));
      float nm = fmaxf(m_run[r], mx);
      float corr = __expf(m_run[r] - nm);
      m_run[r] = nm;
      float rs = 0.f;
#pragma unroll
      for (int n = 0; n < 8; ++n) {
        float p = __expf(sacc[n][r] - nm);
        sacc[n][r] = p;
        rs += p;
      }
#pragma unroll
      for (int msk = 1; msk < 16; msk <<= 1) rs += __shfl_xor(rs, msk);
      l_run[r] = l_run[r] * corr + rs;
      Oacc[0][r] *= corr; Oacc[1][r] *= corr; Oacc[2][r] *= corr; Oacc[3][r] *= corr;
    }
#pragma unroll
    for (int n = 0; n < 8; ++n)
#pragma unroll
      for (int r = 0; r < 4; ++r) {
        int pr = (l >> 4) * 4 + r;
        int pc = n * 16 + c0;
        pw[pr * 128 + ((pc >> 3) ^ (pr & 7)) * 8 + (pc & 7)] = f2bf(sacc[n][r]);
      }
    asm volatile("s_waitcnt lgkmcnt(0)" ::: "memory");
#pragma unroll
    for (int kk = 0; kk < 4; ++kk) {
      int pr = c0;
      short8 ap = *(const short8*)(pw + pr * 128 + ((kk * 4 + kg) ^ cx) * 8);
#pragma unroll
      for (int n = 0; n < 4; ++n) {
        int vr = n * 16 + c0;
        short8 bv = *(const short8*)(Vs + vr * 128 + ((kk * 4 + kg) ^ (vr & 7)) * 8);
        Oacc[n] = __builtin_amdgcn_mfma_f32_16x16x32_bf16(ap, bv, Oacc[n], 0, 0, 0);
      }
    }
    __syncthreads();
    int nx = kv0 + 128;
    if (nx < SEQ) {
#pragma unroll
      for (int i = 0; i < 4; ++i) {
        g2l16(Kg + (size_t)(nx + i * 32) * DH, ksl + i * 2048);
        g2l16(Vg + nx + (size_t)(i * 16) * SEQ, vsl + i * 2048);
      }
    }
  }
#pragma unroll
  for (int r = 0; r < 4; ++r) {
    float inv = 1.f / l_run[r];
    int row = b * SEQ + q0 + w * 16 + (l >> 4) * 4 + r;
#pragma unroll
    for (int n = 0; n < 4; ++n) {
      int col = h * DH + n * 16 + c0;
      H[(size_t)row * HCOLS + col] = f2bf(Oacc[n][r] * inv);
    }
  }
}

// ----------------------------------------------------------------------------
extern "C" void kernel_launch(void* const* d_in, const int* in_sizes, int n_in,
                              void* d_out, int out_size, void* d_ws, size_t ws_size,
                              hipStream_t stream) {
  const float* x     = (const float*)d_in[0];
  const float* gamma = (const float*)d_in[1];
  const float* w_f   = (const float*)d_in[2];
  const float* w_ao  = (const float*)d_in[3];
  const float* w_fo  = (const float*)d_in[4];
  float* out = (float*)d_out;

  char* ws = (char*)d_ws;
  size_t o = 0;
  short* WtF = (short*)(ws + o); o += (size_t)FUSED * DIM * 2;
  short* Wt2 = (short*)(ws + o); o += (size_t)DIM * HCOLS * 2;
  short* xn  = (short*)(ws + o); o += (size_t)NTOK * DIM * 2;
  short* qb  = (short*)(ws + o); o += (size_t)NTOK * AINNER * 2;
  short* kbf = (short*)(ws + o); o += (size_t)NTOK * DH * 2;
  short* vtb = (short*)(ws + o); o += (size_t)NTOK * DH * 2;
  short* H   = (short*)(ws + o); o += (size_t)NTOK * HCOLS * 2;
  short* part = (short*)(ws + o);

  k_prep<<<7456, 256, 0, stream>>>(w_f, w_ao, w_fo, x, gamma, WtF, Wt2, xn);
  p1<<<dim3(37, 16), 512, 131072, stream>>>(xn, WtF, qb, kbf, vtb, H);
  k_attn<<<dim3(32, 16), 256, 0, stream>>>(qb, kbf, vtb, H);
  gemm_s<<<dim3(4, 16, 4), 512, 131072, stream>>>(H, Wt2, part);
  k_red<<<NTOK * DIM / 2048, 256, 0, stream>>>(part, out);
}

// Round 16
// 197.478 us; speedup vs baseline: 1.0646x; 1.0461x over previous
//
#include <hip/hip_runtime.h>
#include <hip/hip_bf16.h>
#include <stdint.h>

#define DIM     1024
#define SEQ     2048
#define NTOK    4096
#define HEADS   8
#define DH      64
#define AINNER  512
#define FFI     4096
#define FUSED   8832
#define HCOLS   4608   // 512 attn-out cols + 4096 gated-ff cols

typedef __attribute__((ext_vector_type(8))) short short8;
typedef __attribute__((ext_vector_type(4))) short short4v;
typedef __attribute__((ext_vector_type(4))) float f32x4;

__device__ __forceinline__ short f2bf(float f) {
  union { float f; uint32_t u; } v; v.f = f;
  uint32_t r = v.u + 0x7fffu + ((v.u >> 16) & 1u);
  return (short)(r >> 16);
}
__device__ __forceinline__ float bf2f(short s) {
  union { uint32_t u; float f; } v; v.u = ((uint32_t)(uint16_t)s) << 16;
  return v.f;
}
__device__ __forceinline__ void g2l16(const void* g, void* l) {
  __builtin_amdgcn_global_load_lds((const __attribute__((address_space(1))) void*)g,
                                   (__attribute__((address_space(3))) void*)l, 16, 0, 0);
}

#define PH_W4 asm volatile("s_waitcnt vmcnt(4)\ns_barrier" ::: "memory")
#define PH_W2 asm volatile("s_waitcnt vmcnt(2)\ns_barrier" ::: "memory")
#define PH_W0 asm volatile("s_waitcnt vmcnt(0)\ns_barrier" ::: "memory")
#define PH_B  asm volatile("s_barrier" ::: "memory")

// ---------------- prep: vectorized transposes + layernorm (R15) -------------
__global__ __launch_bounds__(256) void k_prep(const float* __restrict__ wf,
                                              const float* __restrict__ wao,
                                              const float* __restrict__ wfo,
                                              const float* __restrict__ x,
                                              const float* __restrict__ gamma,
                                              short* __restrict__ WtF,
                                              short* __restrict__ Wt2,
                                              short* __restrict__ xn) {
  __shared__ short tile[64][65];
  __shared__ float red[8];
  int bid = blockIdx.x;
  int t = threadIdx.x;
  if (bid < 3360) {
    bool wfm = bid < 2208;
    int r0, c0, srcld, dstld;
    const float* src0;
    if (wfm) {
      int bx = bid % 138, by = bid / 138;
      c0 = bx * 64; r0 = by * 64;
      src0 = wf; srcld = FUSED; dstld = DIM;
    } else {
      int idx = bid - 2208;
      int by = idx >> 4, bx = idx & 15;
      r0 = by * 64; c0 = bx * 64;
      src0 = (r0 < AINNER) ? wao : wfo;
      if (r0 >= AINNER) r0 -= AINNER;
      srcld = DIM; dstld = HCOLS;
    }
    int tx4 = t & 15, ty = t >> 4;
#pragma unroll
    for (int i = 0; i < 4; ++i) {
      float4 v = *(const float4*)(src0 + (size_t)(r0 + ty + 16 * i) * srcld + c0 + tx4 * 4);
      tile[ty + 16 * i][tx4 * 4 + 0] = f2bf(v.x);
      tile[ty + 16 * i][tx4 * 4 + 1] = f2bf(v.y);
      tile[ty + 16 * i][tx4 * 4 + 2] = f2bf(v.z);
      tile[ty + 16 * i][tx4 * 4 + 3] = f2bf(v.w);
    }
    __syncthreads();
    int rbase = wfm ? (bid / 138) * 64 : ((bid - 2208) >> 4) * 64;
    short* dst = wfm ? WtF : Wt2;
    int oc = t & 15, orw = t >> 4;
#pragma unroll
    for (int i = 0; i < 4; ++i) {
      int orow = orw + 16 * i;
      short4v o;
      o.x = tile[oc * 4 + 0][orow];
      o.y = tile[oc * 4 + 1][orow];
      o.z = tile[oc * 4 + 2][orow];
      o.w = tile[oc * 4 + 3][orow];
      *(short4v*)(dst + (size_t)(c0 + orow) * dstld + rbase + oc * 4) = o;
    }
  } else {
    int row = bid - 3360;
    const float4* xr = (const float4*)(x + (size_t)row * DIM);
    float4 v = xr[t];
    float s = v.x + v.y + v.z + v.w;
    float s2 = v.x * v.x + v.y * v.y + v.z * v.z + v.w * v.w;
#pragma unroll
    for (int m = 1; m < 64; m <<= 1) { s += __shfl_xor(s, m); s2 += __shfl_xor(s2, m); }
    int w = t >> 6;
    if ((t & 63) == 0) { red[w] = s; red[4 + w] = s2; }
    __syncthreads();
    s = red[0] + red[1] + red[2] + red[3];
    s2 = red[4] + red[5] + red[6] + red[7];
    float mu = s * (1.f / DIM);
    float rs = rsqrtf(s2 * (1.f / DIM) - mu * mu + 1e-5f);
    const float4* g4 = (const float4*)gamma;
    float4 g = g4[t];
    short4v o;
    o.x = f2bf((v.x - mu) * rs * g.x);
    o.y = f2bf((v.y - mu) * rs * g.y);
    o.z = f2bf((v.z - mu) * rs * g.z);
    o.w = f2bf((v.w - mu) * rs * g.w);
    ((short4v*)(xn + (size_t)row * DIM))[t] = o;
  }
}

// ---------------- p1: fused qkv + silu(gate)*ffx GEMM -----------------------
// grid (42,16) = 672 blocks = 8 XCD chunks x 84 {64 fused + 20 qkv-half}.
// Fused: 256-row tiles, convoy phases (R13). qkv: 128-row x 128-col half
// blocks (dispatched last in each chunk -> light tail, ~halves makespan tail).
__global__ __launch_bounds__(512, 2) void p1(const short* __restrict__ A,
                                             const short* __restrict__ Bt,
                                             short* __restrict__ qb,
                                             short* __restrict__ kbf,
                                             short* __restrict__ vtb,
                                             short* __restrict__ H) {
  extern __shared__ __align__(16) short S[];
  int tid = threadIdx.x, l = tid & 63, w = tid >> 6;
  int hw = blockIdx.y * 42 + blockIdx.x;      // 672 blocks
  int tile = (hw & 7) * 84 + (hw >> 3);       // XCD-contiguous remap
  int c = tile / 84, j = tile % 84;           // chunk c: 64 fused + 20 qkv
  bool fused = j < 64;
  int bx, mBase;
  if (fused) { int f = c * 64 + j; mBase = (f >> 5) * 256; bx = f & 31; }
  else       { int q = c * 20 + (j - 64); mBase = (q / 5) * 128; bx = 32 + q % 5; }
  int b0row = fused ? (640 + bx * 128) : ((bx - 32) * 128);
  int b1row = 4736 + bx * 128;

  int srow = w * 8 + (l >> 3);
  int cs = (l & 7) ^ (l >> 3);
  const short* Ag = A + (size_t)(mBase + srow) * DIM + cs * 8;
  const short* Bg0 = Bt + (size_t)(b0row + srow) * DIM + cs * 8;
  const short* Bg1 = Bt + (size_t)(b1row + srow) * DIM + cs * 8;
  int dsto = w * 512 + l * 8;

#define STG_A0(kt, db) { _Pragma("unroll") for (int i = 0; i < 2; ++i) \
    g2l16(Ag + (size_t)(i * 64) * DIM + (kt) * 64, S + (db) * 16384 + i * 4096 + dsto); }
#define STG_A1(kt, db) { _Pragma("unroll") for (int i = 2; i < 4; ++i) \
    g2l16(Ag + (size_t)(i * 64) * DIM + (kt) * 64, S + (db) * 16384 + i * 4096 + dsto); }
#define STG_B0(kt, db) { _Pragma("unroll") for (int i = 0; i < 2; ++i) \
    g2l16(Bg0 + (size_t)(i * 64) * DIM + (kt) * 64, S + 32768 + (db) * 16384 + i * 4096 + dsto); }
#define STG_B1(kt, db) { _Pragma("unroll") for (int i = 0; i < 2; ++i) \
    g2l16(Bg1 + (size_t)(i * 64) * DIM + (kt) * 64, S + 32768 + (db) * 16384 + 8192 + i * 4096 + dsto); }

  const int NT = DIM / 64;  // 16
  int c0 = l & 15, kg = l >> 4, cx = l & 7;
  int ch0 = (kg ^ cx) * 8, ch1 = ((4 + kg) ^ cx) * 8;
  int r0 = (l >> 4) * 4;
  f32x4 zero = {0.f, 0.f, 0.f, 0.f};

  if (!fused) {
    // ---- qkv half-block: 128 rows x 128 cols, K=1024 ----
    STG_A0(0, 0); STG_B0(0, 0);
    int ra = (w >> 2) * 64, wn = w & 3;
    f32x4 acc[4][2];
#pragma unroll
    for (int m = 0; m < 4; ++m) { acc[m][0] = zero; acc[m][1] = zero; }
    for (int kt = 0; kt < NT; ++kt) {
      int db = kt & 1, dbn = db ^ 1;
      PH_W0;
      if (kt + 1 < NT) { STG_A0(kt + 1, dbn); STG_B0(kt + 1, dbn); }
      const short* Ab = S + db * 16384;
      const short* Bb = S + 32768 + db * 16384;
#pragma unroll
      for (int kkh = 0; kkh < 2; ++kkh) {
        int ch8 = kkh ? ch1 : ch0;
        short8 b0 = *(const short8*)(Bb + (wn * 32 + c0) * 64 + ch8);
        short8 b1 = *(const short8*)(Bb + (wn * 32 + 16 + c0) * 64 + ch8);
        __builtin_amdgcn_s_setprio(1);
#pragma unroll
        for (int m = 0; m < 4; ++m) {
          short8 a = *(const short8*)(Ab + (ra + m * 16 + c0) * 64 + ch8);
          acc[m][0] = __builtin_amdgcn_mfma_f32_16x16x32_bf16(a, b0, acc[m][0], 0, 0, 0);
          acc[m][1] = __builtin_amdgcn_mfma_f32_16x16x32_bf16(a, b1, acc[m][1], 0, 0, 0);
        }
        __builtin_amdgcn_s_setprio(0);
      }
    }
#pragma unroll
    for (int m = 0; m < 4; ++m)
#pragma unroll
      for (int n = 0; n < 2; ++n)
#pragma unroll
        for (int r = 0; r < 4; ++r) {
          float val = acc[m][n][r];
          int row = mBase + ra + m * 16 + r0 + r;
          int col = (bx - 32) * 128 + wn * 32 + n * 16 + c0;
          if (col < AINNER)
            qb[(size_t)row * AINNER + col] = f2bf(val);
          else if (col < AINNER + DH)
            kbf[(size_t)row * DH + (col - AINNER)] = f2bf(val);
          else
            vtb[((size_t)(row >> 11) * DH + (col - AINNER - DH)) * SEQ +
                (row & (SEQ - 1))] = f2bf(val);
        }
    return;
  }

  // ---- fused path: 4-phase convoy schedule (R13, unchanged) ----
  STG_A0(0, 0); STG_B0(0, 0); STG_B1(0, 0); STG_A1(0, 0);
  int ra = (w >> 2) * 64, rb = (w & 3) * 32;
  f32x4 acc[2][2][4][2];
#pragma unroll
  for (int a = 0; a < 2; ++a)
#pragma unroll
    for (int b = 0; b < 2; ++b)
#pragma unroll
      for (int m = 0; m < 4; ++m)
#pragma unroll
        for (int n = 0; n < 2; ++n) acc[a][b][m][n] = zero;

  for (int kt = 0; kt < NT; ++kt) {
    int db = kt & 1, dbn = db ^ 1;
    bool st = kt + 1 < NT;
    const short* Ab = S + db * 16384;
    const short* Bb = S + 32768 + db * 16384;
    short8 a1[4][2], a2[4][2], bF[2][2], bG[2][2];
    // ph0: (A0, F)
    PH_W4;
#pragma unroll
    for (int m = 0; m < 4; ++m) {
      a1[m][0] = *(const short8*)(Ab + (ra + m * 16 + c0) * 64 + ch0);
      a1[m][1] = *(const short8*)(Ab + (ra + m * 16 + c0) * 64 + ch1);
    }
#pragma unroll
    for (int n = 0; n < 2; ++n) {
      bF[n][0] = *(const short8*)(Bb + (rb + n * 16 + c0) * 64 + ch0);
      bF[n][1] = *(const short8*)(Bb + (rb + n * 16 + c0) * 64 + ch1);
    }
    if (st) STG_A0(kt + 1, dbn);
    PH_B;
    __builtin_amdgcn_s_setprio(1);
#pragma unroll
    for (int m = 0; m < 4; ++m)
#pragma unroll
      for (int n = 0; n < 2; ++n) {
        acc[0][0][m][n] = __builtin_amdgcn_mfma_f32_16x16x32_bf16(a1[m][0], bF[n][0], acc[0][0][m][n], 0, 0, 0);
        acc[0][0][m][n] = __builtin_amdgcn_mfma_f32_16x16x32_bf16(a1[m][1], bF[n][1], acc[0][0][m][n], 0, 0, 0);
      }
    __builtin_amdgcn_s_setprio(0);
    // ph1: (A0, G)
    if (st) PH_W4; else PH_W2;
#pragma unroll
    for (int n = 0; n < 2; ++n) {
      bG[n][0] = *(const short8*)(Bb + 8192 + (rb + n * 16 + c0) * 64 + ch0);
      bG[n][1] = *(const short8*)(Bb + 8192 + (rb + n * 16 + c0) * 64 + ch1);
    }
    if (st) STG_B0(kt + 1, dbn);
    PH_B;
    __builtin_amdgcn_s_setprio(1);
#pragma unroll
    for (int m = 0; m < 4; ++m)
#pragma unroll
      for (int n = 0; n < 2; ++n) {
        acc[0][1][m][n] = __builtin_amdgcn_mfma_f32_16x16x32_bf16(a1[m][0], bG[n][0], acc[0][1][m][n], 0, 0, 0);
        acc[0][1][m][n] = __builtin_amdgcn_mfma_f32_16x16x32_bf16(a1[m][1], bG[n][1], acc[0][1][m][n], 0, 0, 0);
      }
    __builtin_amdgcn_s_setprio(0);
    // ph2: (A1, G)
    if (st) PH_W4; else PH_W0;
#pragma unroll
    for (int m = 0; m < 4; ++m) {
      a2[m][0] = *(const short8*)(Ab + 8192 + (ra + m * 16 + c0) * 64 + ch0);
      a2[m][1] = *(const short8*)(Ab + 8192 + (ra + m * 16 + c0) * 64 + ch1);
    }
    if (st) STG_B1(kt + 1, dbn);
    PH_B;
    __builtin_amdgcn_s_setprio(1);
#pragma unroll
    for (int m = 0; m < 4; ++m)
#pragma unroll
      for (int n = 0; n < 2; ++n) {
        acc[1][1][m][n] = __builtin_amdgcn_mfma_f32_16x16x32_bf16(a2[m][0], bG[n][0], acc[1][1][m][n], 0, 0, 0);
        acc[1][1][m][n] = __builtin_amdgcn_mfma_f32_16x16x32_bf16(a2[m][1], bG[n][1], acc[1][1][m][n], 0, 0, 0);
      }
    __builtin_amdgcn_s_setprio(0);
    // ph3: (A1, F) — register-only
    if (st) STG_A1(kt + 1, dbn);
    __builtin_amdgcn_s_setprio(1);
#pragma unroll
    for (int m = 0; m < 4; ++m)
#pragma unroll
      for (int n = 0; n < 2; ++n) {
        acc[1][0][m][n] = __builtin_amdgcn_mfma_f32_16x16x32_bf16(a2[m][0], bF[n][0], acc[1][0][m][n], 0, 0, 0);
        acc[1][0][m][n] = __builtin_amdgcn_mfma_f32_16x16x32_bf16(a2[m][1], bF[n][1], acc[1][0][m][n], 0, 0, 0);
      }
    __builtin_amdgcn_s_setprio(0);
  }
#undef STG_A0
#undef STG_A1
#undef STG_B0
#undef STG_B1

#pragma unroll
  for (int a = 0; a < 2; ++a)
#pragma unroll
    for (int m = 0; m < 4; ++m)
#pragma unroll
      for (int n = 0; n < 2; ++n)
#pragma unroll
        for (int r = 0; r < 4; ++r) {
          int row = mBase + a * 128 + ra + m * 16 + r0 + r;
          int col = bx * 128 + rb + n * 16 + c0;
          float g = acc[a][1][m][n][r];
          float sg = g / (1.f + __expf(-g));
          H[(size_t)row * HCOLS + AINNER + col] = f2bf(sg * acc[a][0][m][n][r]);
        }
}

// ---------------- out-GEMM: 256x256 split-K=4, convoy phases (R13) ----------
__global__ __launch_bounds__(512, 2) void gemm_s(const short* __restrict__ A,
                                                 const short* __restrict__ Bt,
                                                 short* __restrict__ part) {
  extern __shared__ __align__(16) short S[];
  int tid = threadIdx.x, l = tid & 63, w = tid >> 6;
  int hw = (blockIdx.z * 16 + blockIdx.y) * 4 + blockIdx.x;  // 256 blocks
  int tile = (hw & 7) * 32 + (hw >> 3);
  int bx = tile & 3, by = (tile >> 2) & 15, bz = tile >> 6;
  int mBase = by * 256, nBase = bx * 256;
  int kOff = bz * 1152;

  int srow = w * 8 + (l >> 3);
  int cs = (l & 7) ^ (l >> 3);
  const short* Ag = A + (size_t)(mBase + srow) * HCOLS + kOff + cs * 8;
  const short* Bg = Bt + (size_t)(nBase + srow) * HCOLS + kOff + cs * 8;
  int dsto = w * 512 + l * 8;

#define SG_A0(kt, db) { _Pragma("unroll") for (int i = 0; i < 2; ++i) \
    g2l16(Ag + (size_t)(i * 64) * HCOLS + (kt) * 64, S + (db) * 16384 + i * 4096 + dsto); }
#define SG_A1(kt, db) { _Pragma("unroll") for (int i = 2; i < 4; ++i) \
    g2l16(Ag + (size_t)(i * 64) * HCOLS + (kt) * 64, S + (db) * 16384 + i * 4096 + dsto); }
#define SG_B0(kt, db) { _Pragma("unroll") for (int i = 0; i < 2; ++i) \
    g2l16(Bg + (size_t)(i * 64) * HCOLS + (kt) * 64, S + 32768 + (db) * 16384 + i * 4096 + dsto); }
#define SG_B1(kt, db) { _Pragma("unroll") for (int i = 2; i < 4; ++i) \
    g2l16(Bg + (size_t)(i * 64) * HCOLS + (kt) * 64, S + 32768 + (db) * 16384 + i * 4096 + dsto); }

  const int NT = 18;
  SG_A0(0, 0); SG_B0(0, 0); SG_B1(0, 0); SG_A1(0, 0);

  int c0 = l & 15, kg = l >> 4, cx = l & 7;
  int ch0 = (kg ^ cx) * 8, ch1 = ((4 + kg) ^ cx) * 8;
  int ra = (w >> 2) * 64, rb = (w & 3) * 32;
  f32x4 zero = {0.f, 0.f, 0.f, 0.f};
  f32x4 acc[2][2][4][2];
#pragma unroll
  for (int a = 0; a < 2; ++a)
#pragma unroll
    for (int b = 0; b < 2; ++b)
#pragma unroll
      for (int m = 0; m < 4; ++m)
#pragma unroll
        for (int n = 0; n < 2; ++n) acc[a][b][m][n] = zero;

  for (int kt = 0; kt < NT; ++kt) {
    int db = kt & 1, dbn = db ^ 1;
    bool st = kt + 1 < NT;
    const short* Ab = S + db * 16384;
    const short* Bb = S + 32768 + db * 16384;
    short8 a1[4][2], a2[4][2], bF[2][2], bG[2][2];
    PH_W4;
#pragma unroll
    for (int m = 0; m < 4; ++m) {
      a1[m][0] = *(const short8*)(Ab + (ra + m * 16 + c0) * 64 + ch0);
      a1[m][1] = *(const short8*)(Ab + (ra + m * 16 + c0) * 64 + ch1);
    }
#pragma unroll
    for (int n = 0; n < 2; ++n) {
      bF[n][0] = *(const short8*)(Bb + (rb + n * 16 + c0) * 64 + ch0);
      bF[n][1] = *(const short8*)(Bb + (rb + n * 16 + c0) * 64 + ch1);
    }
    if (st) SG_A0(kt + 1, dbn);
    PH_B;
    __builtin_amdgcn_s_setprio(1);
#pragma unroll
    for (int m = 0; m < 4; ++m)
#pragma unroll
      for (int n = 0; n < 2; ++n) {
        acc[0][0][m][n] = __builtin_amdgcn_mfma_f32_16x16x32_bf16(a1[m][0], bF[n][0], acc[0][0][m][n], 0, 0, 0);
        acc[0][0][m][n] = __builtin_amdgcn_mfma_f32_16x16x32_bf16(a1[m][1], bF[n][1], acc[0][0][m][n], 0, 0, 0);
      }
    __builtin_amdgcn_s_setprio(0);
    if (st) PH_W4; else PH_W2;
#pragma unroll
    for (int n = 0; n < 2; ++n) {
      bG[n][0] = *(const short8*)(Bb + 8192 + (rb + n * 16 + c0) * 64 + ch0);
      bG[n][1] = *(const short8*)(Bb + 8192 + (rb + n * 16 + c0) * 64 + ch1);
    }
    if (st) SG_B0(kt + 1, dbn);
    PH_B;
    __builtin_amdgcn_s_setprio(1);
#pragma unroll
    for (int m = 0; m < 4; ++m)
#pragma unroll
      for (int n = 0; n < 2; ++n) {
        acc[0][1][m][n] = __builtin_amdgcn_mfma_f32_16x16x32_bf16(a1[m][0], bG[n][0], acc[0][1][m][n], 0, 0, 0);
        acc[0][1][m][n] = __builtin_amdgcn_mfma_f32_16x16x32_bf16(a1[m][1], bG[n][1], acc[0][1][m][n], 0, 0, 0);
      }
    __builtin_amdgcn_s_setprio(0);
    if (st) PH_W4; else PH_W0;
#pragma unroll
    for (int m = 0; m < 4; ++m) {
      a2[m][0] = *(const short8*)(Ab + 8192 + (ra + m * 16 + c0) * 64 + ch0);
      a2[m][1] = *(const short8*)(Ab + 8192 + (ra + m * 16 + c0) * 64 + ch1);
    }
    if (st) SG_B1(kt + 1, dbn);
    PH_B;
    __builtin_amdgcn_s_setprio(1);
#pragma unroll
    for (int m = 0; m < 4; ++m)
#pragma unroll
      for (int n = 0; n < 2; ++n) {
        acc[1][1][m][n] = __builtin_amdgcn_mfma_f32_16x16x32_bf16(a2[m][0], bG[n][0], acc[1][1][m][n], 0, 0, 0);
        acc[1][1][m][n] = __builtin_amdgcn_mfma_f32_16x16x32_bf16(a2[m][1], bG[n][1], acc[1][1][m][n], 0, 0, 0);
      }
    __builtin_amdgcn_s_setprio(0);
    if (st) SG_A1(kt + 1, dbn);
    __builtin_amdgcn_s_setprio(1);
#pragma unroll
    for (int m = 0; m < 4; ++m)
#pragma unroll
      for (int n = 0; n < 2; ++n) {
        acc[1][0][m][n] = __builtin_amdgcn_mfma_f32_16x16x32_bf16(a2[m][0], bF[n][0], acc[1][0][m][n], 0, 0, 0);
        acc[1][0][m][n] = __builtin_amdgcn_mfma_f32_16x16x32_bf16(a2[m][1], bF[n][1], acc[1][0][m][n], 0, 0, 0);
      }
    __builtin_amdgcn_s_setprio(0);
  }
#undef SG_A0
#undef SG_A1
#undef SG_B0
#undef SG_B1

  int r0 = (l >> 4) * 4;
#pragma unroll
  for (int a = 0; a < 2; ++a)
#pragma unroll
    for (int b = 0; b < 2; ++b)
#pragma unroll
      for (int m = 0; m < 4; ++m)
#pragma unroll
        for (int n = 0; n < 2; ++n)
#pragma unroll
          for (int r = 0; r < 4; ++r) {
            int row = mBase + a * 128 + ra + m * 16 + r0 + r;
            int col = nBase + b * 128 + rb + n * 16 + c0;
            part[(size_t)bz * (NTOK * DIM) + (size_t)row * DIM + col] = f2bf(acc[a][b][m][n][r]);
          }
}

__global__ __launch_bounds__(256) void k_red(const short* __restrict__ part,
                                             float* __restrict__ out) {
  int i = (blockIdx.x * 256 + threadIdx.x) * 8;
  float s[8] = {0.f, 0.f, 0.f, 0.f, 0.f, 0.f, 0.f, 0.f};
#pragma unroll
  for (int ks = 0; ks < 4; ++ks) {
    short8 v = *(const short8*)(part + (size_t)ks * (NTOK * DIM) + i);
#pragma unroll
    for (int jj = 0; jj < 8; ++jj) s[jj] += bf2f(v[jj]);
  }
  float4 lo = {s[0], s[1], s[2], s[3]};
  float4 hi = {s[4], s[5], s[6], s[7]};
  *(float4*)(out + i) = lo;
  *(float4*)(out + i + 4) = hi;
}

// ---------------- flash attention (unchanged) -------------------------------
__global__ __launch_bounds__(256) void k_attn(const short* __restrict__ qb,
                                              const short* __restrict__ kb,
                                              const short* __restrict__ vt,
                                              short* __restrict__ H) {
  __shared__ __align__(16) short Qs[64 * 64];
  __shared__ __align__(16) short Ks[128 * 64];
  __shared__ __align__(16) short Vs[64 * 128];
  __shared__ __align__(16) short Ps[4][16 * 128];
  int t = threadIdx.x, l = t & 63, w = t >> 6;
  int qt = blockIdx.x, bh = blockIdx.y;
  int b = bh >> 3, h = bh & 7;
  int q0 = qt * 64;

  int srow = w * 8 + (l >> 3);
  int schunk = (l & 7) ^ (l >> 3);
  {
    const short* Qg = qb + (size_t)(b * SEQ + q0 + srow) * AINNER + h * DH + schunk * 8;
    short* qs = Qs + w * 512 + l * 8;
#pragma unroll
    for (int i = 0; i < 2; ++i) g2l16(Qg + (size_t)(i * 32) * AINNER, qs + i * 2048);
  }
  const short* Kg = kb + (size_t)(b * SEQ + srow) * DH + schunk * 8;
  short* ksl = Ks + w * 512 + l * 8;
  int vrow = w * 4 + (l >> 4);
  int vchunk = (l & 15) ^ (vrow & 7);
  const short* Vg = vt + (size_t)b * DH * SEQ + (size_t)vrow * SEQ + vchunk * 8;
  short* vsl = Vs + w * 512 + l * 8;

#pragma unroll
  for (int i = 0; i < 4; ++i) {
    g2l16(Kg + (size_t)(i * 32) * DH, ksl + i * 2048);
    g2l16(Vg + (size_t)(i * 16) * SEQ, vsl + i * 2048);
  }

  float m_run[4], l_run[4];
  f32x4 zero = {0.f, 0.f, 0.f, 0.f};
  f32x4 Oacc[4];
#pragma unroll
  for (int r = 0; r < 4; ++r) { m_run[r] = -1e30f; l_run[r] = 0.f; }
#pragma unroll
  for (int n = 0; n < 4; ++n) Oacc[n] = zero;

  int c0 = l & 15, kg = l >> 4, cx = l & 7;
  short* pw = Ps[w];

  for (int kv0 = 0; kv0 < SEQ; kv0 += 128) {
    asm volatile("s_waitcnt vmcnt(0)\ns_barrier" ::: "memory");

    f32x4 sacc[8];
#pragma unroll
    for (int n = 0; n < 8; ++n) sacc[n] = zero;
#pragma unroll
    for (int kk = 0; kk < 2; ++kk) {
      int rr = w * 16 + c0;
      short8 aq = *(const short8*)(Qs + rr * 64 + ((kk * 4 + kg) ^ cx) * 8);
#pragma unroll
      for (int n = 0; n < 8; ++n) {
        int kr = n * 16 + c0;
        short8 bk = *(const short8*)(Ks + kr * 64 + ((kk * 4 + kg) ^ cx) * 8);
        sacc[n] = __builtin_amdgcn_mfma_f32_16x16x32_bf16(aq, bk, sacc[n], 0, 0, 0);
      }
    }
#pragma unroll
    for (int r = 0; r < 4; ++r) {
      float mx = -1e30f;
#pragma unroll
      for (int n = 0; n < 8; ++n) {
        sacc[n][r] *= 0.125f;
        mx = fmaxf(mx, sacc[n][r]);
      }
#pragma unroll
      for (int msk = 1; msk < 16; msk <<= 1) mx = fmaxf(mx, __shfl_xor(mx, msk));
      float nm = fmaxf(m_run[r], mx);
      float corr = __expf(m_run[r] - nm);
      m_run[r] = nm;
      float rs = 0.f;
#pragma unroll
      for (int n = 0; n < 8; ++n) {
        float p = __expf(sacc[n][r] - nm);
        sacc[n][r] = p;
        rs += p;
      }
#pragma unroll
      for (int msk = 1; msk < 16; msk <<= 1) rs += __shfl_xor(rs, msk);
      l_run[r] = l_run[r] * corr + rs;
      Oacc[0][r] *= corr; Oacc[1][r] *= corr; Oacc[2][r] *= corr; Oacc[3][r] *= corr;
    }
#pragma unroll
    for (int n = 0; n < 8; ++n)
#pragma unroll
      for (int r = 0; r < 4; ++r) {
        int pr = (l >> 4) * 4 + r;
        int pc = n * 16 + c0;
        pw[pr * 128 + ((pc >> 3) ^ (pr & 7)) * 8 + (pc & 7)] = f2bf(sacc[n][r]);
      }
    asm volatile("s_waitcnt lgkmcnt(0)" ::: "memory");
#pragma unroll
    for (int kk = 0; kk < 4; ++kk) {
      int pr = c0;
      short8 ap = *(const short8*)(pw + pr * 128 + ((kk * 4 + kg) ^ cx) * 8);
#pragma unroll
      for (int n = 0; n < 4; ++n) {
        int vr = n * 16 + c0;
        short8 bv = *(const short8*)(Vs + vr * 128 + ((kk * 4 + kg) ^ (vr & 7)) * 8);
        Oacc[n] = __builtin_amdgcn_mfma_f32_16x16x32_bf16(ap, bv, Oacc[n], 0, 0, 0);
      }
    }
    __syncthreads();
    int nx = kv0 + 128;
    if (nx < SEQ) {
#pragma unroll
      for (int i = 0; i < 4; ++i) {
        g2l16(Kg + (size_t)(nx + i * 32) * DH, ksl + i * 2048);
        g2l16(Vg + nx + (size_t)(i * 16) * SEQ, vsl + i * 2048);
      }
    }
  }
#pragma unroll
  for (int r = 0; r < 4; ++r) {
    float inv = 1.f / l_run[r];
    int row = b * SEQ + q0 + w * 16 + (l >> 4) * 4 + r;
#pragma unroll
    for (int n = 0; n < 4; ++n) {
      int col = h * DH + n * 16 + c0;
      H[(size_t)row * HCOLS + col] = f2bf(Oacc[n][r] * inv);
    }
  }
}

// ----------------------------------------------------------------------------
extern "C" void kernel_launch(void* const* d_in, const int* in_sizes, int n_in,
                              void* d_out, int out_size, void* d_ws, size_t ws_size,
                              hipStream_t stream) {
  const float* x     = (const float*)d_in[0];
  const float* gamma = (const float*)d_in[1];
  const float* w_f   = (const float*)d_in[2];
  const float* w_ao  = (const float*)d_in[3];
  const float* w_fo  = (const float*)d_in[4];
  float* out = (float*)d_out;

  char* ws = (char*)d_ws;
  size_t o = 0;
  short* WtF = (short*)(ws + o); o += (size_t)FUSED * DIM * 2;
  short* Wt2 = (short*)(ws + o); o += (size_t)DIM * HCOLS * 2;
  short* xn  = (short*)(ws + o); o += (size_t)NTOK * DIM * 2;
  short* qb  = (short*)(ws + o); o += (size_t)NTOK * AINNER * 2;
  short* kbf = (short*)(ws + o); o += (size_t)NTOK * DH * 2;
  short* vtb = (short*)(ws + o); o += (size_t)NTOK * DH * 2;
  short* H   = (short*)(ws + o); o += (size_t)NTOK * HCOLS * 2;
  short* part = (short*)(ws + o);

  k_prep<<<7456, 256, 0, stream>>>(w_f, w_ao, w_fo, x, gamma, WtF, Wt2, xn);
  p1<<<dim3(42, 16), 512, 131072, stream>>>(xn, WtF, qb, kbf, vtb, H);
  k_attn<<<dim3(32, 16), 256, 0, stream>>>(qb, kbf, vtb, H);
  gemm_s<<<dim3(4, 16, 4), 512, 131072, stream>>>(H, Wt2, part);
  k_red<<<NTOK * DIM / 2048, 256, 0, stream>>>(part, out);
}